// Round 1
// baseline (162.678 us; speedup 1.0000x reference)
//
#include <hip/hip_runtime.h>

#define N 224        // image size
#define M 32         // CUT (number of sine modes)
#define NPIX (N * N) // 50176 = 196 * 256
#define PI_F 3.14159265358979323846f

// Stage 1: compute both scalar fields, displacement, and the per-pixel
// bilinear gather table (corner offsets + fractional weights).
// One block per row y, one thread per column x.
__global__ __launch_bounds__(256) void field_kernel(
    const float* __restrict__ Fx, const float* __restrict__ Fy,
    int4* __restrict__ offs, float2* __restrict__ wgt)
{
    __shared__ float cx[M][M];
    __shared__ float cy[M][M];
    __shared__ float sy[M];

    const int t = threadIdx.x;
    const int y = blockIdx.x;

    // c = F * e, where e[i][j] = (r < M+0.5) / r, r = sqrt((i+1)^2+(j+1)^2)
    for (int idx = t; idx < M * M; idx += 256) {
        const int i = idx / M, j = idx % M;
        const float fi = (float)(i + 1), fj = (float)(j + 1);
        const float r = sqrtf(fi * fi + fj * fj);
        const float e = (r < (float)M + 0.5f) ? (1.0f / r) : 0.0f;
        cx[i][j] = Fx[idx] * e;
        cy[i][j] = Fy[idx] * e;
    }
    if (t < M) {
        const float ys = (float)y / (float)(N - 1);
        sy[t] = sinf(PI_F * ys * (float)(t + 1));
    }
    __syncthreads();

    if (t >= N) return;  // no further barriers below
    const int x = t;

    // per-thread x-basis: s[x][i] = sin(pi * xs[x] * (i+1))
    float sx[M];
    const float xsv = (float)x / (float)(N - 1);
#pragma unroll
    for (int i = 0; i < M; ++i)
        sx[i] = sinf(PI_F * xsv * (float)(i + 1));

    // field[y][x] = sum_j s[y][j] * (sum_i c[i][j] * s[x][i])
    float u = 0.0f, v = 0.0f;
#pragma unroll 1
    for (int j = 0; j < M; ++j) {
        float tx = 0.0f, ty = 0.0f;
#pragma unroll
        for (int i = 0; i < M; ++i) {
            tx = fmaf(cx[i][j], sx[i], tx);
            ty = fmaf(cy[i][j], sx[i], ty);
        }
        const float syj = sy[j];
        u = fmaf(syj, tx, u);
        v = fmaf(syj, ty, v);
    }

    // dx = sqrt(T)*u*n = 0.1 * 224 * u
    const float dxv = 22.4f * u;
    const float dyv = 22.4f * v;
    const float xn = fminf(fmaxf((float)x + dxv, 0.0f), (float)(N - 1));
    const float yn = fminf(fmaxf((float)y + dyv, 0.0f), (float)(N - 1));
    const float xff = floorf(xn), yff = floorf(yn);
    const int xf = (int)xff, yf = (int)yff;
    const int xc = (int)ceilf(xn), yc = (int)ceilf(yn);

    const int pix = y * N + x;
    offs[pix] = make_int4(yf * N + xf, yf * N + xc, yc * N + xf, yc * N + xc);
    wgt[pix]  = make_float2(xn - xff, yn - yff);
}

// Stage 2: bilinear gather for every (plane, pixel).
// grid = (NPIX/256, B*C); block = 256. Writes fully coalesced.
__global__ __launch_bounds__(256) void remap_kernel(
    const float* __restrict__ x, const int4* __restrict__ offs,
    const float2* __restrict__ wgt, float* __restrict__ out)
{
    const int pix = blockIdx.x * 256 + threadIdx.x;  // < 50176
    const int plane = blockIdx.y;                    // < 384
    const float* img = x + (size_t)plane * NPIX;

    const int4 o = offs[pix];
    const float2 w = wgt[pix];

    const float v00 = img[o.x];
    const float v01 = img[o.y];
    const float v10 = img[o.z];
    const float v11 = img[o.w];

    const float omx = 1.0f - w.x, omy = 1.0f - w.y;
    // exact reference formulation
    const float val = omy * omx * v00 + omy * w.x * v01
                    + w.y * omx * v10 + w.y * w.x * v11;

    out[(size_t)plane * NPIX + pix] = val;
}

extern "C" void kernel_launch(void* const* d_in, const int* in_sizes, int n_in,
                              void* d_out, int out_size, void* d_ws, size_t ws_size,
                              hipStream_t stream) {
    const float* x  = (const float*)d_in[0];   // [128,3,224,224]
    const float* Fx = (const float*)d_in[1];   // [32,32]
    const float* Fy = (const float*)d_in[2];   // [32,32]
    float* out = (float*)d_out;

    int4*   offs = (int4*)d_ws;
    float2* wgt  = (float2*)((char*)d_ws + (size_t)NPIX * sizeof(int4));

    field_kernel<<<N, 256, 0, stream>>>(Fx, Fy, offs, wgt);

    const int planes = 128 * 3;
    remap_kernel<<<dim3(NPIX / 256, planes), 256, 0, stream>>>(x, offs, wgt, out);
}

// Round 2
// 134.724 us; speedup vs baseline: 1.2075x; 1.2075x over previous
//
#include <hip/hip_runtime.h>

#define N 224        // image size
#define M 32         // CUT (number of sine modes)
#define NPIX (N * N) // 50176 = 196 * 256
#define NCHUNK 196   // 256-pixel chunks per plane
#define NPLANE 384   // 128 * 3
#define NXCD 8
#define PI_F 3.14159265358979323846f

// Stage 1: compute both scalar fields, displacement, and the per-pixel
// bilinear gather table (corner offsets + fractional weights).
// One block per row y, one thread per column x.
__global__ __launch_bounds__(256) void field_kernel(
    const float* __restrict__ Fx, const float* __restrict__ Fy,
    int4* __restrict__ offs, float2* __restrict__ wgt)
{
    __shared__ float cx[M][M];
    __shared__ float cy[M][M];
    __shared__ float sy[M];

    const int t = threadIdx.x;
    const int y = blockIdx.x;

    // c = F * e, where e[i][j] = (r < M+0.5) / r, r = sqrt((i+1)^2+(j+1)^2)
    for (int idx = t; idx < M * M; idx += 256) {
        const int i = idx / M, j = idx % M;
        const float fi = (float)(i + 1), fj = (float)(j + 1);
        const float r = sqrtf(fi * fi + fj * fj);
        const float e = (r < (float)M + 0.5f) ? (1.0f / r) : 0.0f;
        cx[i][j] = Fx[idx] * e;
        cy[i][j] = Fy[idx] * e;
    }
    if (t < M) {
        const float ys = (float)y / (float)(N - 1);
        sy[t] = sinf(PI_F * ys * (float)(t + 1));
    }
    __syncthreads();

    if (t >= N) return;  // no further barriers below
    const int x = t;

    // per-thread x-basis: s[x][i] = sin(pi * xs[x] * (i+1))
    float sx[M];
    const float xsv = (float)x / (float)(N - 1);
#pragma unroll
    for (int i = 0; i < M; ++i)
        sx[i] = sinf(PI_F * xsv * (float)(i + 1));

    // field[y][x] = sum_j s[y][j] * (sum_i c[i][j] * s[x][i])
    float u = 0.0f, v = 0.0f;
#pragma unroll 1
    for (int j = 0; j < M; ++j) {
        float tx = 0.0f, ty = 0.0f;
#pragma unroll
        for (int i = 0; i < M; ++i) {
            tx = fmaf(cx[i][j], sx[i], tx);
            ty = fmaf(cy[i][j], sx[i], ty);
        }
        const float syj = sy[j];
        u = fmaf(syj, tx, u);
        v = fmaf(syj, ty, v);
    }

    // dx = sqrt(T)*u*n = 0.1 * 224 * u
    const float dxv = 22.4f * u;
    const float dyv = 22.4f * v;
    const float xn = fminf(fmaxf((float)x + dxv, 0.0f), (float)(N - 1));
    const float yn = fminf(fmaxf((float)y + dyv, 0.0f), (float)(N - 1));
    const float xff = floorf(xn), yff = floorf(yn);
    const int xf = (int)xff, yf = (int)yff;
    const int xc = (int)ceilf(xn), yc = (int)ceilf(yn);

    const int pix = y * N + x;
    offs[pix] = make_int4(yf * N + xf, yf * N + xc, yc * N + xf, yc * N + xc);
    wgt[pix]  = make_float2(xn - xff, yn - yff);
}

// Stage 2: bilinear gather for every (plane, pixel).
// 1-D grid of NCHUNK*NPLANE blocks, XCD-clustered so that all 196 chunks of
// a plane land on the SAME XCD (blocks round-robin across 8 XCDs by id):
//   xcd   = bid % 8
//   local = bid / 8           (9408 per XCD)
//   plane = xcd + 8*(local/196)   -> 48 whole planes per XCD
//   chunk = local % 196
// Each XCD streams one 200 KB plane through its private L2 at a time ->
// x fetched from HBM exactly once (was 3.8x with the scattered mapping).
__global__ __launch_bounds__(256) void remap_kernel(
    const float* __restrict__ x, const int4* __restrict__ offs,
    const float2* __restrict__ wgt, float* __restrict__ out)
{
    const int bid   = blockIdx.x;
    const int xcd   = bid % NXCD;
    const int local = bid / NXCD;
    const int plane = xcd + NXCD * (local / NCHUNK);
    const int chunk = local % NCHUNK;
    const int pix   = chunk * 256 + threadIdx.x;

    const float* img = x + (size_t)plane * NPIX;

    const int4 o = offs[pix];
    const float2 w = wgt[pix];

    const float v00 = img[o.x];
    const float v01 = img[o.y];
    const float v10 = img[o.z];
    const float v11 = img[o.w];

    const float omx = 1.0f - w.x, omy = 1.0f - w.y;
    // exact reference formulation
    const float val = omy * omx * v00 + omy * w.x * v01
                    + w.y * omx * v10 + w.y * w.x * v11;

    out[(size_t)plane * NPIX + pix] = val;
}

extern "C" void kernel_launch(void* const* d_in, const int* in_sizes, int n_in,
                              void* d_out, int out_size, void* d_ws, size_t ws_size,
                              hipStream_t stream) {
    const float* x  = (const float*)d_in[0];   // [128,3,224,224]
    const float* Fx = (const float*)d_in[1];   // [32,32]
    const float* Fy = (const float*)d_in[2];   // [32,32]
    float* out = (float*)d_out;

    int4*   offs = (int4*)d_ws;
    float2* wgt  = (float2*)((char*)d_ws + (size_t)NPIX * sizeof(int4));

    field_kernel<<<N, 256, 0, stream>>>(Fx, Fy, offs, wgt);

    remap_kernel<<<NCHUNK * NPLANE, 256, 0, stream>>>(x, offs, wgt, out);
}